// Round 8
// baseline (341.583 us; speedup 1.0000x reference)
//
#include <hip/hip_runtime.h>
#include <math.h>

#define NH 16
#define NKV 4
#define HD 128
#define DIM 2048
#define GQ 4   // NH/NKV
#define EPS 1.1920928955078125e-07f

typedef unsigned short u16;
using bf16x8 = __attribute__((ext_vector_type(8))) short;
using f16x4  = __attribute__((ext_vector_type(4))) _Float16;
using f32x4  = __attribute__((ext_vector_type(4))) float;

__device__ inline float fast_exp2(float x) { return __builtin_amdgcn_exp2f(x); }

__device__ inline short f2bf(float f) {
    unsigned u = __builtin_bit_cast(unsigned, f);
    return (short)((u + 0x7FFFu + ((u >> 16) & 1u)) >> 16);
}
__device__ inline u16 f2h(float f) {
    _Float16 h = (_Float16)f;
    return __builtin_bit_cast(u16, h);
}

#define ASYNC_LOAD16(g, l)                                                        \
    __builtin_amdgcn_global_load_lds(                                             \
        (const __attribute__((address_space(1))) unsigned*)(g),                   \
        (__attribute__((address_space(3))) unsigned*)(l), 16, 0, 0)

#define SCHED_FENCE() __builtin_amdgcn_sched_barrier(0)
#define WAIT_LGKM0()  asm volatile("s_waitcnt lgkmcnt(0)" ::: "memory")
#define WAIT_VM(N)    asm volatile("s_waitcnt vmcnt(" #N ")" ::: "memory")

// ------- fused fp32 -> bf16 convert (all 5 tensors) + RoPE tables -----------
__global__ __launch_bounds__(256) void cvt_fused(
    const float* __restrict__ x,  const float* __restrict__ wq,
    const float* __restrict__ wk, const float* __restrict__ wv,
    const float* __restrict__ wp,
    u16* __restrict__ x16, u16* __restrict__ wqkv, u16* __restrict__ wp16,
    float* __restrict__ ct, float* __restrict__ st, float l2b64,
    int nx4, int total, int nblk_cvt) {
    if ((int)blockIdx.x >= nblk_cvt) {
        // RoPE table part: [T][64]
        const int idx = (blockIdx.x - nblk_cvt) * 256 + threadIdx.x;
        const int t = idx >> 6;
        const int j = idx & 63;
        const float inv_freq = fast_exp2(-(float)j * l2b64);
        const float fr = (float)t * inv_freq;
        ct[idx] = cosf(fr);
        st[idx] = sinf(fr);
        return;
    }
    int i = blockIdx.x * 256 + threadIdx.x;
    if (i >= total) return;
    const int nw4 = DIM * DIM / 4;          // 1048576
    const int nk4 = (NKV * HD) * DIM / 4;   // 262144
    const float4* s4;
    ushort4* d4;
    if (i < nx4) {
        s4 = (const float4*)x + i; d4 = (ushort4*)x16 + i;
    } else {
        int j = i - nx4;
        if (j < nw4) {
            s4 = (const float4*)wq + j; d4 = (ushort4*)wqkv + j;
        } else {
            j -= nw4;
            if (j < nk4) {
                s4 = (const float4*)wk + j;
                d4 = (ushort4*)wqkv + (size_t)2048 * DIM / 4 + j;
            } else {
                j -= nk4;
                if (j < nk4) {
                    s4 = (const float4*)wv + j;
                    d4 = (ushort4*)wqkv + (size_t)2560 * DIM / 4 + j;
                } else {
                    j -= nk4;
                    s4 = (const float4*)wp + j; d4 = (ushort4*)wp16 + j;
                }
            }
        }
    }
    float4 f = *s4;
    ushort4 o;
    o.x = (u16)f2bf(f.x); o.y = (u16)f2bf(f.y);
    o.z = (u16)f2bf(f.z); o.w = (u16)f2bf(f.w);
    *d4 = o;
}

// ===== BMx256 4-phase GEMM: counted vmcnt (T4) + in-pair early ds_reads =====
// Round-3 barrier skeleton (2 barriers/phase -- load-bearing, round-6 lesson)
// + m196/m201 interleave: each phase's fragment reads are issued INSIDE the
// previous phase's barrier pair (after its lgkmcnt(0), before its MFMA), so
// they drain in the LDS pipe while the SIMDs issue MFMA.
// Fixed-role register sets (no runtime indexing): a0,a1 (A kk0/kk1),
// bA=b00, bB=b01, bC=b10, bD=b11 -- identical assignment every K-tile.
// vmcnt: P0-end vm(MT)  retires b1,b3 of CURRENT tile (needed by P1's early
//                       read of b10); cross-wave via P0 trailing barrier.
//        P2-end vm(2)   retires a*,b0,b2 of NEXT tile (needed by P3's early
//                       read of a0',b00'); cross-wave via P2 trailing barrier.
// In-flight b1',b3' DMA writes touch only b1/b3 rows -- disjoint from P3's
// a-row / b0-row reads.  Queue never drains to 0 in the loop.
#define BN 256
#define BKT 64
#define NKT (DIM / BKT)   // 32

template <int EPI, int MT>
__global__ __launch_bounds__(512, 2) void gemm256(
    const u16* __restrict__ A, const u16* __restrict__ W,
    float* __restrict__ C, int N,                       // EPI==0: plain fp32 C
    u16* __restrict__ q16, u16* __restrict__ k16,       // EPI==1: fused QKV
    u16* __restrict__ vt16,
    const float* __restrict__ ctab, const float* __restrict__ stab,
    const float* __restrict__ q_gain, int T) {
    __shared__ u16 As[2][MT * 64 * BKT];
    __shared__ u16 Bs[2][BN * BKT];

    const int tid  = threadIdx.x;
    const int wid  = tid >> 6;
    const int lane = tid & 63;
    const int l16  = lane & 15;
    const int quad = lane >> 4;
    const int wm   = wid >> 1;          // 0..3  (MT*16 rows each)
    const int wn   = wid & 1;           // 0..1  (128 cols each)
    const int m0   = blockIdx.x * (MT * 64);
    const int n0   = blockIdx.y * BN;
    const int K    = DIM;

    const int srow = lane >> 3;                     // 0..7
    const int scol = ((lane & 7) ^ srow) * 8;       // pre-swizzled source col
    const u16* pa = A + (size_t)(m0 + srow) * K + scol;
    const u16* pw = W + (size_t)(n0 + srow) * K + scol;

    const int ca0 = ((quad)     ^ (l16 & 7)) * 8;   // kk = 0
    const int ca1 = ((4 + quad) ^ (l16 & 7)) * 8;   // kk = 1

    f32x4 acc[MT][8];
#pragma unroll
    for (int i = 0; i < MT; i++)
#pragma unroll
        for (int j = 0; j < 8; j++) acc[i][j] = (f32x4){0.f, 0.f, 0.f, 0.f};

    // fixed-role fragment sets
    bf16x8 a0[MT], a1[MT], bA[4], bB[4], bC[4], bD[4];

    // ---- prologue: stage tile 0 (age order a*, b0,b2, b1,b3) ----
#pragma unroll
    for (int r = 0; r < MT; r++)
        ASYNC_LOAD16(pa + (size_t)(r * 64 + wid * 8) * K, &As[0][(r * 64 + wid * 8) * BKT]);
    ASYNC_LOAD16(pw + (size_t)(0 * 64 + wid * 8) * K, &Bs[0][(0 * 64 + wid * 8) * BKT]);
    ASYNC_LOAD16(pw + (size_t)(2 * 64 + wid * 8) * K, &Bs[0][(2 * 64 + wid * 8) * BKT]);
    ASYNC_LOAD16(pw + (size_t)(1 * 64 + wid * 8) * K, &Bs[0][(1 * 64 + wid * 8) * BKT]);
    ASYNC_LOAD16(pw + (size_t)(3 * 64 + wid * 8) * K, &Bs[0][(3 * 64 + wid * 8) * BKT]);
    WAIT_VM(2);                 // a*, b0, b2 landed; b1,b3 stay in flight
    SCHED_FENCE();
    __builtin_amdgcn_s_barrier();
    SCHED_FENCE();
    // pre-issue tile-0 P0 fragments (a0, b00 -> bA)
#pragma unroll
    for (int mt = 0; mt < MT; mt++)
        a0[mt] = *(const bf16x8*)&As[0][(wm * (MT * 16) + mt * 16 + l16) * BKT + ca0];
#pragma unroll
    for (int nt = 0; nt < 4; nt++)
        bA[nt] = *(const bf16x8*)&Bs[0][(wn * 128 + nt * 16 + l16) * BKT + ca0];

#pragma unroll 1
    for (int kt = 0; kt < NKT; kt++) {
        const int cur = kt & 1;
        const u16* Ac = &As[cur][0];
        const u16* Bc = &Bs[cur][0];
        const u16* Anr = &As[cur ^ 1][0];   // next-tile frag reads (P3)
        const u16* Bnr = &Bs[cur ^ 1][0];
        u16* An = &As[cur ^ 1][0];
        u16* Bn = &Bs[cur ^ 1][0];
        // last tile wraps to k=0: dummy-but-valid loads keep waits uniform
        const size_t ko = (size_t)((kt + 1) & (NKT - 1)) * BKT;

        // ---- P0: MFMA a0 x bA(b00); early-read a1,bB(b01); stage a' ----
        {
#pragma unroll
            for (int r = 0; r < MT; r++)
                ASYNC_LOAD16(pa + (size_t)(r * 64 + wid * 8) * K + ko,
                             &An[(r * 64 + wid * 8) * BKT]);
            SCHED_FENCE();
            __builtin_amdgcn_s_barrier();
            WAIT_LGKM0();            // a0,bA done (issued last phase)
            SCHED_FENCE();
#pragma unroll
            for (int mt = 0; mt < MT; mt++)
                a1[mt] = *(const bf16x8*)&Ac[(wm * (MT * 16) + mt * 16 + l16) * BKT + ca1];
#pragma unroll
            for (int nt = 0; nt < 4; nt++)
                bB[nt] = *(const bf16x8*)&Bc[(wn * 128 + nt * 16 + l16) * BKT + ca1];
            SCHED_FENCE();
            __builtin_amdgcn_s_setprio(1);
#pragma unroll
            for (int mt = 0; mt < MT; mt++)
#pragma unroll
                for (int nt = 0; nt < 4; nt++)
                    acc[mt][nt] = __builtin_amdgcn_mfma_f32_16x16x32_bf16(
                        a0[mt], bA[nt], acc[mt][nt], 0, 0, 0);
            __builtin_amdgcn_s_setprio(0);
            if constexpr (MT == 4) { WAIT_VM(4); } else { WAIT_VM(2); }
            SCHED_FENCE();
            __builtin_amdgcn_s_barrier();   // cross-wave: b1,b3 of kt landed
        }

        // ---- P1: MFMA a1 x bB(b01); early-read bC(b10); stage b0',b2' ----
        {
            ASYNC_LOAD16(pw + (size_t)(0 * 64 + wid * 8) * K + ko,
                         &Bn[(0 * 64 + wid * 8) * BKT]);
            ASYNC_LOAD16(pw + (size_t)(2 * 64 + wid * 8) * K + ko,
                         &Bn[(2 * 64 + wid * 8) * BKT]);
            SCHED_FENCE();
            __builtin_amdgcn_s_barrier();
            WAIT_LGKM0();            // a1,bB done
            SCHED_FENCE();
#pragma unroll
            for (int nt = 0; nt < 4; nt++)
                bC[nt] = *(const bf16x8*)&Bc[(wn * 128 + (nt + 4) * 16 + l16) * BKT + ca0];
            SCHED_FENCE();
            __builtin_amdgcn_s_setprio(1);
#pragma unroll
            for (int mt = 0; mt < MT; mt++)
#pragma unroll
                for (int nt = 0; nt < 4; nt++)
                    acc[mt][nt] = __builtin_amdgcn_mfma_f32_16x16x32_bf16(
                        a1[mt], bB[nt], acc[mt][nt], 0, 0, 0);
            __builtin_amdgcn_s_setprio(0);
            SCHED_FENCE();
            __builtin_amdgcn_s_barrier();
        }

        // ---- P2: MFMA a0 x bC(b10); early-read bD(b11); stage b1',b3' ----
        {
            ASYNC_LOAD16(pw + (size_t)(1 * 64 + wid * 8) * K + ko,
                         &Bn[(1 * 64 + wid * 8) * BKT]);
            ASYNC_LOAD16(pw + (size_t)(3 * 64 + wid * 8) * K + ko,
                         &Bn[(3 * 64 + wid * 8) * BKT]);
            SCHED_FENCE();
            __builtin_amdgcn_s_barrier();
            WAIT_LGKM0();            // bC done
            SCHED_FENCE();
#pragma unroll
            for (int nt = 0; nt < 4; nt++)
                bD[nt] = *(const bf16x8*)&Bc[(wn * 128 + (nt + 4) * 16 + l16) * BKT + ca1];
            SCHED_FENCE();
            __builtin_amdgcn_s_setprio(1);
#pragma unroll
            for (int mt = 0; mt < MT; mt++)
#pragma unroll
                for (int nt = 0; nt < 4; nt++)
                    acc[mt][nt + 4] = __builtin_amdgcn_mfma_f32_16x16x32_bf16(
                        a0[mt], bC[nt], acc[mt][nt + 4], 0, 0, 0);
            __builtin_amdgcn_s_setprio(0);
            WAIT_VM(2);   // retire a*,b0,b2 of NEXT tile; b1,b3 in flight
            SCHED_FENCE();
            __builtin_amdgcn_s_barrier();   // cross-wave for P3's early reads
        }

        // ---- P3: MFMA a1 x bD(b11); early-read next a0,bA(b00') ----
        {
            SCHED_FENCE();
            __builtin_amdgcn_s_barrier();
            WAIT_LGKM0();            // bD done
            SCHED_FENCE();
#pragma unroll
            for (int mt = 0; mt < MT; mt++)
                a0[mt] = *(const bf16x8*)&Anr[(wm * (MT * 16) + mt * 16 + l16) * BKT + ca0];
#pragma unroll
            for (int nt = 0; nt < 4; nt++)
                bA[nt] = *(const bf16x8*)&Bnr[(wn * 128 + nt * 16 + l16) * BKT + ca0];
            SCHED_FENCE();
            __builtin_amdgcn_s_setprio(1);
#pragma unroll
            for (int mt = 0; mt < MT; mt++)
#pragma unroll
                for (int nt = 0; nt < 4; nt++)
                    acc[mt][nt + 4] = __builtin_amdgcn_mfma_f32_16x16x32_bf16(
                        a1[mt], bD[nt], acc[mt][nt + 4], 0, 0, 0);
            __builtin_amdgcn_s_setprio(0);
            SCHED_FENCE();
            __builtin_amdgcn_s_barrier();
        }
    }
    WAIT_VM(0);   // drain wrap-around dummy loads before epilogue/endpgm

    // --------------------------- epilogues ---------------------------------
    if constexpr (EPI == 0) {
#pragma unroll
        for (int mt = 0; mt < MT; mt++)
#pragma unroll
            for (int nt = 0; nt < 8; nt++)
#pragma unroll
                for (int r = 0; r < 4; r++)
                    C[(size_t)(m0 + wm * (MT * 16) + mt * 16 + quad * 4 + r) * N +
                      n0 + wn * 128 + nt * 16 + l16] = acc[mt][nt][r];
    } else {
        const int nb = n0 + wn * 128;           // head-aligned column base
        if (nb < 2560) {                        // ---- Q or K: RMSNorm + RoPE
            const bool isQ = (nb < 2048);
            const float gval =
                isQ ? (q_gain[nb >> 7] * 0.08838834764831843f * 1.4426950408889634f)
                    : 1.0f;
#pragma unroll
            for (int mt = 0; mt < MT; mt++) {
#pragma unroll
                for (int r = 0; r < 4; r++) {
                    float s = 0.f;
#pragma unroll
                    for (int nt = 0; nt < 8; nt++) {
                        float a = acc[mt][nt][r];
                        s = fmaf(a, a, s);
                    }
                    s += __shfl_xor(s, 1);
                    s += __shfl_xor(s, 2);
                    s += __shfl_xor(s, 4);
                    s += __shfl_xor(s, 8);
                    const float scale = rsqrtf(s * (1.0f / HD) + EPS) * gval;
                    const int m = m0 + wm * (MT * 16) + mt * 16 + quad * 4 + r;
                    const int t = m & (T - 1);
                    const float* ct = ctab + t * 64;
                    const float* st = stab + t * 64;
                    u16* dst = isQ ? (q16 + (size_t)m * 2048 + nb)
                                   : (k16 + (size_t)m * 512 + (nb - 2048));
#pragma unroll
                    for (int nt = 0; nt < 4; nt++) {
                        const int j = nt * 16 + l16;
                        const float c = ct[j], sn = st[j];
                        const float x1 = acc[mt][nt][r] * scale;
                        const float x2 = acc[mt][nt + 4][r] * scale;
                        dst[j]      = (u16)f2bf(x1 * c + x2 * sn);
                        dst[j + 64] = (u16)f2bf(x2 * c - x1 * sn);
                    }
                }
            }
        } else {                                // ---- V: f16, transposed [d][t]
#pragma unroll
            for (int mt = 0; mt < MT; mt++) {
                const int mb = m0 + wm * (MT * 16) + mt * 16 + quad * 4;
                const int b = mb >> 11;          // T == 2048
                const int t0 = mb & (T - 1);
#pragma unroll
                for (int nt = 0; nt < 8; nt++) {
                    const int dcol = nb - 2560 + nt * 16 + l16;
                    const int kvh = dcol >> 7;
                    const int d = dcol & (HD - 1);
                    ushort4 o;
                    o.x = f2h(acc[mt][nt][0]);
                    o.y = f2h(acc[mt][nt][1]);
                    o.z = f2h(acc[mt][nt][2]);
                    o.w = f2h(acc[mt][nt][3]);
                    *(ushort4*)(vt16 + ((size_t)((b * NKV + kvh) * HD + d)) * T + t0) = o;
                }
            }
        }
    }
}

// ------ flash attention v5 (proven 75.5 us): 8 waves, QT=128 ----------------
// S^T = K Q^T (bf16 x32); softmax in registers (exp2, defer-max THR=8);
// O^T = V^T P^T (f16 x16).  XOR-swizzled K/V LDS, DMA double buffer.
#define QT 128
#define SK 64

__global__ __launch_bounds__(512) void flash5(const u16* __restrict__ q16,
                                              const u16* __restrict__ k16,
                                              const u16* __restrict__ vt16,
                                              u16* __restrict__ y16, int T) {
    __shared__ u16 Ks[2][SK * 128];
    __shared__ u16 Vt[2][HD * 64];

    const int tid = threadIdx.x;
    const int wave = tid >> 6;        // 0..7
    const int lane = tid & 63;
    const int l16 = lane & 15;
    const int quad = lane >> 4;

    const int bid = blockIdx.x;
    const int bh = bid & 31;          // b*NH + h
    const int qi = bid >> 5;          // 0..nqt-1
    const int nqt = T / QT;           // 16
    const int qt = (qi < (nqt >> 1)) ? qi : (nqt - 1 - (qi - (nqt >> 1)));
    const int h = bh & 15;
    const int b = bh >> 4;
    const int kv = h / GQ;

    const u16* kg = k16 + ((size_t)b * T * NKV + kv) * HD;
    const u16* vg = vt16 + (size_t)(b * NKV + kv) * HD * T;

    const int krow_in_seg = lane >> 4;          // 0..3
    const int kclog_base = lane & 15;           // phys chunk; logical = phys ^ (r&15)
    const int vrow_in_seg = lane >> 3;          // 0..7
    const int vclog = (lane & 7) ^ (lane >> 3); // logical chunk

    const int q0 = qt * QT;
    const int qglob = q0 + wave * 16 + l16;
    const int nts = q0 / SK + 2;      // two diagonal tiles

    bf16x8 qf[4];
    {
        const u16* qp = q16 + ((size_t)(b * T + qglob) * NH + h) * HD;
#pragma unroll
        for (int kc = 0; kc < 4; kc++)
            qf[kc] = *(const bf16x8*)(qp + kc * 32 + quad * 8);
    }

    f32x4 of[8];
#pragma unroll
    for (int i = 0; i < 8; i++) of[i] = (f32x4){0.f, 0.f, 0.f, 0.f};
    float m_i = -1e30f, l_i = 0.0f;

    // preload tile 0: 16 K segs + 16 V segs, 2+2 per wave
#pragma unroll
    for (int j = 0; j < 2; j++) {
        const int seg = wave * 2 + j;
        const int r = seg * 4 + krow_in_seg;
        const int clog = kclog_base ^ (r & 15);
        ASYNC_LOAD16(kg + (size_t)r * (NKV * HD) + clog * 8, &Ks[0][seg * 512]);
        const int d = seg * 8 + vrow_in_seg;
        ASYNC_LOAD16(vg + (size_t)d * T + vclog * 8, &Vt[0][seg * 512]);
    }

    for (int it = 0; it < nts; it++) {
        const int cur = it & 1;
        __syncthreads();   // drains DMA for tile `it` (one full phase in flight)

        if (it + 1 < nts) {
            const int s1 = (it + 1) * SK;
#pragma unroll
            for (int j = 0; j < 2; j++) {
                const int seg = wave * 2 + j;
                const int r = seg * 4 + krow_in_seg;
                const int clog = kclog_base ^ (r & 15);
                ASYNC_LOAD16(kg + (size_t)(s1 + r) * (NKV * HD) + clog * 8,
                             &Ks[cur ^ 1][seg * 512]);
                const int d = seg * 8 + vrow_in_seg;
                ASYNC_LOAD16(vg + (size_t)d * T + s1 + vclog * 8,
                             &Vt[cur ^ 1][seg * 512]);
            }
        }

        // waves 0-3 are fully masked on the last diagonal tile: skip compute
        if (it == nts - 1 && wave < 4) continue;

        // S^T = K Q^T
        f32x4 sf[4];
#pragma unroll
        for (int st = 0; st < 4; st++) sf[st] = (f32x4){0.f, 0.f, 0.f, 0.f};
#pragma unroll
        for (int kc = 0; kc < 4; kc++)
#pragma unroll
            for (int st = 0; st < 4; st++) {
                const int row = st * 16 + l16;
                bf16x8 kf = *(const bf16x8*)
                    &Ks[cur][row * 128 + (((kc * 4 + quad) ^ l16) * 8)];
                sf[st] = __builtin_amdgcn_mfma_f32_16x16x32_bf16(kf, qf[kc], sf[st], 0, 0, 0);
            }

        if (it >= nts - 2) {  // diagonal tiles: causal mask
            const int s0 = it * SK;
#pragma unroll
            for (int st = 0; st < 4; st++)
#pragma unroll
                for (int r = 0; r < 4; r++)
                    if (s0 + st * 16 + quad * 4 + r > qglob) sf[st][r] = -1e30f;
        }

        float tm = -1e30f;
#pragma unroll
        for (int st = 0; st < 4; st++)
#pragma unroll
            for (int r = 0; r < 4; r++) tm = fmaxf(tm, sf[st][r]);
        tm = fmaxf(tm, __shfl_xor(tm, 16));
        tm = fmaxf(tm, __shfl_xor(tm, 32));

        // defer-max (T13): only rescale when max grew by > 8 (log2 units)
        if (__ballot(tm > m_i + 8.0f)) {
            const float mnew = fmaxf(m_i, tm);
            const float alpha = fast_exp2(m_i - mnew);
            m_i = mnew;
            l_i *= alpha;
#pragma unroll
            for (int dt = 0; dt < 8; dt++)
#pragma unroll
                for (int r = 0; r < 4; r++) of[dt][r] *= alpha;
        }

        f16x4 pf[4];
        float ls = 0.0f;
#pragma unroll
        for (int st = 0; st < 4; st++)
#pragma unroll
            for (int r = 0; r < 4; r++) {
                float e = fast_exp2(sf[st][r] - m_i);
                ls += e;
                pf[st][r] = (_Float16)e;
            }
        ls += __shfl_xor(ls, 16);
        ls += __shfl_xor(ls, 32);
        l_i += ls;

        // O^T += V^T P^T
#pragma unroll
        for (int st = 0; st < 4; st++) {
            const int clog = st * 2 + (quad >> 1);
#pragma unroll
            for (int dt = 0; dt < 8; dt++) {
                const int d = dt * 16 + l16;
                const int phys = clog ^ (l16 & 7);
                f16x4 va = *(const f16x4*)
                    &Vt[cur][d * 64 + phys * 8 + (quad & 1) * 4];
                of[dt] = __builtin_amdgcn_mfma_f32_16x16x16f16(va, pf[st], of[dt], 0, 0, 0);
            }
        }
    }

    const float inv = 1.0f / l_i;
    u16* yp = y16 + ((size_t)(b * T + qglob) * NH + h) * HD + quad * 4;
#pragma unroll
    for (int dt = 0; dt < 8; dt++) {
        ushort4 o;
        o.x = (u16)f2bf(of[dt][0] * inv);
        o.y = (u16)f2bf(of[dt][1] * inv);
        o.z = (u16)f2bf(of[dt][2] * inv);
        o.w = (u16)f2bf(of[dt][3] * inv);
        *(ushort4*)(yp + dt * 16) = o;
    }
}

// ---------------------------------------------------------------------------
extern "C" void kernel_launch(void* const* d_in, const int* in_sizes, int n_in,
                              void* d_out, int out_size, void* d_ws, size_t ws_size,
                              hipStream_t stream) {
    const float* x      = (const float*)d_in[0];
    const float* Wq     = (const float*)d_in[1];
    const float* Wk     = (const float*)d_in[2];
    const float* Wv     = (const float*)d_in[3];
    const float* Wp     = (const float*)d_in[4];
    const float* q_gain = (const float*)d_in[5];
    float* out = (float*)d_out;

    const int B = 2;
    const int BT = in_sizes[0] / DIM;      // 4096
    const int T = BT / B;                  // 2048
    const int KD = NKV * HD;               // 512

    u16* x16   = (u16*)d_ws;                        // BT*DIM        (later y16)
    u16* wqkv  = x16 + (size_t)BT * DIM;            // 3072*DIM
    u16* wp16  = wqkv + (size_t)3072 * DIM;         // DIM*DIM
    u16* q16   = wp16 + (size_t)DIM * DIM;          // BT*DIM
    u16* k16   = q16 + (size_t)BT * DIM;            // BT*KD
    u16* vt16  = k16 + (size_t)BT * KD;             // BT*KD
    float* ctab = (float*)(vt16 + (size_t)BT * KD); // T*64
    float* stab = ctab + (size_t)T * 64;            // T*64
    u16* y16   = x16;

    double base = 10000.0;
    if (T > 1024) base = 10000.0 * pow((double)T / 1024.0, 128.0 / 126.0);
    const float l2b64 = (float)(log2(base) / 64.0);

    const int nx4  = BT * DIM / 4;
    const int total4 = nx4 + 2 * (DIM * DIM / 4) + 2 * (KD * DIM / 4);
    const int nblk_cvt = (total4 + 255) / 256;
    const int nblk_rope = (T * 64 + 255) / 256;

    cvt_fused<<<nblk_cvt + nblk_rope, 256, 0, stream>>>(
        x, Wq, Wk, Wv, Wp, x16, wqkv, wp16, ctab, stab, l2b64, nx4, total4, nblk_cvt);

    gemm256<1, 4><<<dim3(BT / 256, 3072 / BN), 512, 0, stream>>>(
        x16, wqkv, nullptr, 0, q16, k16, vt16, ctab, stab, q_gain, T);

    flash5<<<32 * (T / QT), 512, 0, stream>>>(q16, k16, vt16, y16, T);

    gemm256<0, 2><<<dim3(BT / 128, DIM / BN), 512, 0, stream>>>(
        y16, wp16, out, DIM, nullptr, nullptr, nullptr, nullptr, nullptr, nullptr, T);
}

// Round 9
// 331.339 us; speedup vs baseline: 1.0309x; 1.0309x over previous
//
#include <hip/hip_runtime.h>
#include <math.h>

#define NH 16
#define NKV 4
#define HD 128
#define DIM 2048
#define GQ 4   // NH/NKV
#define EPS 1.1920928955078125e-07f

typedef unsigned short u16;
using bf16x8 = __attribute__((ext_vector_type(8))) short;
using f16x4  = __attribute__((ext_vector_type(4))) _Float16;
using f32x4  = __attribute__((ext_vector_type(4))) float;

__device__ inline float fast_exp2(float x) { return __builtin_amdgcn_exp2f(x); }

__device__ inline short f2bf(float f) {
    unsigned u = __builtin_bit_cast(unsigned, f);
    return (short)((u + 0x7FFFu + ((u >> 16) & 1u)) >> 16);
}
__device__ inline u16 f2h(float f) {
    _Float16 h = (_Float16)f;
    return __builtin_bit_cast(u16, h);
}

#define ASYNC_LOAD16(g, l)                                                        \
    __builtin_amdgcn_global_load_lds(                                             \
        (const __attribute__((address_space(1))) unsigned*)(g),                   \
        (__attribute__((address_space(3))) unsigned*)(l), 16, 0, 0)

#define SCHED_FENCE() __builtin_amdgcn_sched_barrier(0)
#define WAIT_VM(N)    asm volatile("s_waitcnt vmcnt(" #N ")" ::: "memory")

// ------- fused fp32 -> bf16 convert (all 5 tensors) + RoPE tables -----------
__global__ __launch_bounds__(256) void cvt_fused(
    const float* __restrict__ x,  const float* __restrict__ wq,
    const float* __restrict__ wk, const float* __restrict__ wv,
    const float* __restrict__ wp,
    u16* __restrict__ x16, u16* __restrict__ wqkv, u16* __restrict__ wp16,
    float* __restrict__ ct, float* __restrict__ st, float l2b64,
    int nx4, int total, int nblk_cvt) {
    if ((int)blockIdx.x >= nblk_cvt) {
        // RoPE table part: [T][64]
        const int idx = (blockIdx.x - nblk_cvt) * 256 + threadIdx.x;
        const int t = idx >> 6;
        const int j = idx & 63;
        const float inv_freq = fast_exp2(-(float)j * l2b64);
        const float fr = (float)t * inv_freq;
        ct[idx] = cosf(fr);
        st[idx] = sinf(fr);
        return;
    }
    int i = blockIdx.x * 256 + threadIdx.x;
    if (i >= total) return;
    const int nw4 = DIM * DIM / 4;          // 1048576
    const int nk4 = (NKV * HD) * DIM / 4;   // 262144
    const float4* s4;
    ushort4* d4;
    if (i < nx4) {
        s4 = (const float4*)x + i; d4 = (ushort4*)x16 + i;
    } else {
        int j = i - nx4;
        if (j < nw4) {
            s4 = (const float4*)wq + j; d4 = (ushort4*)wqkv + j;
        } else {
            j -= nw4;
            if (j < nk4) {
                s4 = (const float4*)wk + j;
                d4 = (ushort4*)wqkv + (size_t)2048 * DIM / 4 + j;
            } else {
                j -= nk4;
                if (j < nk4) {
                    s4 = (const float4*)wv + j;
                    d4 = (ushort4*)wqkv + (size_t)2560 * DIM / 4 + j;
                } else {
                    j -= nk4;
                    s4 = (const float4*)wp + j; d4 = (ushort4*)wp16 + j;
                }
            }
        }
    }
    float4 f = *s4;
    ushort4 o;
    o.x = (u16)f2bf(f.x); o.y = (u16)f2bf(f.y);
    o.z = (u16)f2bf(f.z); o.w = (u16)f2bf(f.w);
    *d4 = o;
}

// ======= BMx256 GEMM, BK=32, QUAD-buffered LDS, 1 barrier / K-tile ==========
// 8 waves (4M x 2N).  Per K-tile (BK=32): issue L global_load_lds for tile
// kt+3 (3-tile-deep prefetch, ~2.5 K-tiles of flight before drain), read
// 12 fragment ds_read_b128, one 32-MFMA cluster under setprio, then
// WAIT_VM(2L) (retires tile kt+1 only -- queue never drains) + s_barrier.
// Round-8 lesson: waits with <2 phases of flight kill the pipeline; this
// structure's only wait has ~2.5 K-tiles of flight.
// LDS [*][32] bf16 rows (64B): phys_chunk = quad ^ (row&3) balances all 32
// banks exactly (32B/bank per wave-read); staged via linear LDS dest +
// pre-swizzled global source (row+128 reuses the same swizzle: 128%4==0).
// MT=4: BM=256, L=4 loads/iter, vm(8).  MT=2: BM=128, L=3, vm(6).
#define BN 256
#define BKT2 32
#define NT2 (DIM / BKT2)   // 64

template <int EPI, int MT>
__global__ __launch_bounds__(512, 2) void gemm32(
    const u16* __restrict__ A, const u16* __restrict__ W,
    float* __restrict__ C, int N,                       // EPI==0: plain fp32 C
    u16* __restrict__ q16, u16* __restrict__ k16,       // EPI==1: fused QKV
    u16* __restrict__ vt16,
    const float* __restrict__ ctab, const float* __restrict__ stab,
    const float* __restrict__ q_gain, int T) {
    __shared__ u16 As[4][MT * 64 * BKT2];   // MT=4: 64KB, MT=2: 32KB
    __shared__ u16 Bs[4][BN * BKT2];        // 64KB

    const int tid  = threadIdx.x;
    const int wid  = tid >> 6;
    const int lane = tid & 63;
    const int l16  = lane & 15;
    const int quad = lane >> 4;
    const int wm   = wid >> 1;          // 0..3  (MT*16 rows each)
    const int wn   = wid & 1;           // 0..1  (128 cols each)
    const int m0   = blockIdx.x * (MT * 64);
    const int n0   = blockIdx.y * BN;
    const int K    = DIM;

    // staging: thread tid covers chunk tid -> row tid>>2, phys chunk tid&3
    // pre-swizzled source col (elements): ((tid&3) ^ (row&3)) * 8
    const int srow = tid >> 2;                           // 0..127
    const int sc   = (((tid & 3) ^ (srow & 3)) * 8);
    const u16* pa = A + (size_t)(m0 + srow) * K + sc;
    const u16* pw = W + (size_t)(n0 + srow) * K + sc;

    // fragment ds_read col offset (elements): row&3 == l16&3
    const int ca = (quad ^ (l16 & 3)) * 8;

    f32x4 acc[MT][8];
#pragma unroll
    for (int i = 0; i < MT; i++)
#pragma unroll
        for (int j = 0; j < 8; j++) acc[i][j] = (f32x4){0.f, 0.f, 0.f, 0.f};

    // ---- prologue: stage tiles 0,1,2 (in order; L loads per tile) ----
#pragma unroll
    for (int p = 0; p < 3; p++) {
        const size_t ko = (size_t)p * BKT2;
        u16* Ab = &As[p][0];
        u16* Bb = &Bs[p][0];
        ASYNC_LOAD16(pa + ko, Ab + tid * 8);
        if constexpr (MT == 4) {
            ASYNC_LOAD16(pa + (size_t)128 * K + ko, Ab + tid * 8 + 4096);
        }
        ASYNC_LOAD16(pw + ko, Bb + tid * 8);
        ASYNC_LOAD16(pw + (size_t)128 * K + ko, Bb + tid * 8 + 4096);
    }
    if constexpr (MT == 4) { WAIT_VM(8); } else { WAIT_VM(6); }
    SCHED_FENCE();
    __builtin_amdgcn_s_barrier();
    SCHED_FENCE();

#pragma unroll 1
    for (int kt = 0; kt < NT2; kt++) {
        const u16* Ab = &As[kt & 3][0];
        const u16* Bb = &Bs[kt & 3][0];

        // issue tile kt+3 (wraps to k<96 on the tail: valid dummy loads)
        {
            const size_t ko = (size_t)((kt + 3) & (NT2 - 1)) * BKT2;
            u16* An = &As[(kt + 3) & 3][0];
            u16* Bn = &Bs[(kt + 3) & 3][0];
            ASYNC_LOAD16(pa + ko, An + tid * 8);
            if constexpr (MT == 4) {
                ASYNC_LOAD16(pa + (size_t)128 * K + ko, An + tid * 8 + 4096);
            }
            ASYNC_LOAD16(pw + ko, Bn + tid * 8);
            ASYNC_LOAD16(pw + (size_t)128 * K + ko, Bn + tid * 8 + 4096);
        }

        // fragment reads for tile kt (compiler inserts fine lgkmcnt waits)
        bf16x8 af[MT], bf[8];
#pragma unroll
        for (int mt = 0; mt < MT; mt++)
            af[mt] = *(const bf16x8*)&Ab[(wm * (MT * 16) + mt * 16 + l16) * BKT2 + ca];
#pragma unroll
        for (int nt = 0; nt < 8; nt++)
            bf[nt] = *(const bf16x8*)&Bb[(wn * 128 + nt * 16 + l16) * BKT2 + ca];

        __builtin_amdgcn_s_setprio(1);
#pragma unroll
        for (int mt = 0; mt < MT; mt++)
#pragma unroll
            for (int nt = 0; nt < 8; nt++)
                acc[mt][nt] = __builtin_amdgcn_mfma_f32_16x16x32_bf16(
                    af[mt], bf[nt], acc[mt][nt], 0, 0, 0);
        __builtin_amdgcn_s_setprio(0);

        // retire tile kt+1 (own loads, ~2.5 K-tiles of flight); never drain
        if constexpr (MT == 4) { WAIT_VM(8); } else { WAIT_VM(6); }
        SCHED_FENCE();
        __builtin_amdgcn_s_barrier();   // all waves: kt+1 ready; buf[kt&3] readers done
        SCHED_FENCE();
    }
    WAIT_VM(0);   // drain wrap-around dummy loads before epilogue

    // --------------------------- epilogues ---------------------------------
    if constexpr (EPI == 0) {
#pragma unroll
        for (int mt = 0; mt < MT; mt++)
#pragma unroll
            for (int nt = 0; nt < 8; nt++)
#pragma unroll
                for (int r = 0; r < 4; r++)
                    C[(size_t)(m0 + wm * (MT * 16) + mt * 16 + quad * 4 + r) * N +
                      n0 + wn * 128 + nt * 16 + l16] = acc[mt][nt][r];
    } else {
        const int nb = n0 + wn * 128;           // head-aligned column base
        if (nb < 2560) {                        // ---- Q or K: RMSNorm + RoPE
            const bool isQ = (nb < 2048);
            const float gval =
                isQ ? (q_gain[nb >> 7] * 0.08838834764831843f * 1.4426950408889634f)
                    : 1.0f;
#pragma unroll
            for (int mt = 0; mt < MT; mt++) {
#pragma unroll
                for (int r = 0; r < 4; r++) {
                    float s = 0.f;
#pragma unroll
                    for (int nt = 0; nt < 8; nt++) {
                        float a = acc[mt][nt][r];
                        s = fmaf(a, a, s);
                    }
                    s += __shfl_xor(s, 1);
                    s += __shfl_xor(s, 2);
                    s += __shfl_xor(s, 4);
                    s += __shfl_xor(s, 8);
                    const float scale = rsqrtf(s * (1.0f / HD) + EPS) * gval;
                    const int m = m0 + wm * (MT * 16) + mt * 16 + quad * 4 + r;
                    const int t = m & (T - 1);
                    const float* ct = ctab + t * 64;
                    const float* st = stab + t * 64;
                    u16* dst = isQ ? (q16 + (size_t)m * 2048 + nb)
                                   : (k16 + (size_t)m * 512 + (nb - 2048));
#pragma unroll
                    for (int nt = 0; nt < 4; nt++) {
                        const int j = nt * 16 + l16;
                        const float c = ct[j], sn = st[j];
                        const float x1 = acc[mt][nt][r] * scale;
                        const float x2 = acc[mt][nt + 4][r] * scale;
                        dst[j]      = (u16)f2bf(x1 * c + x2 * sn);
                        dst[j + 64] = (u16)f2bf(x2 * c - x1 * sn);
                    }
                }
            }
        } else {                                // ---- V: f16, transposed [d][t]
#pragma unroll
            for (int mt = 0; mt < MT; mt++) {
                const int mb = m0 + wm * (MT * 16) + mt * 16 + quad * 4;
                const int b = mb >> 11;          // T == 2048
                const int t0 = mb & (T - 1);
#pragma unroll
                for (int nt = 0; nt < 8; nt++) {
                    const int dcol = nb - 2560 + nt * 16 + l16;
                    const int kvh = dcol >> 7;
                    const int d = dcol & (HD - 1);
                    ushort4 o;
                    o.x = f2h(acc[mt][nt][0]);
                    o.y = f2h(acc[mt][nt][1]);
                    o.z = f2h(acc[mt][nt][2]);
                    o.w = f2h(acc[mt][nt][3]);
                    *(ushort4*)(vt16 + ((size_t)((b * NKV + kvh) * HD + d)) * T + t0) = o;
                }
            }
        }
    }
}

// ------ flash attention v5 (proven 75.5 us): 8 waves, QT=128 ----------------
// S^T = K Q^T (bf16 x32); softmax in registers (exp2, defer-max THR=8);
// O^T = V^T P^T (f16 x16).  XOR-swizzled K/V LDS, DMA double buffer.
#define QT 128
#define SK 64

__global__ __launch_bounds__(512) void flash5(const u16* __restrict__ q16,
                                              const u16* __restrict__ k16,
                                              const u16* __restrict__ vt16,
                                              u16* __restrict__ y16, int T) {
    __shared__ u16 Ks[2][SK * 128];
    __shared__ u16 Vt[2][HD * 64];

    const int tid = threadIdx.x;
    const int wave = tid >> 6;        // 0..7
    const int lane = tid & 63;
    const int l16 = lane & 15;
    const int quad = lane >> 4;

    const int bid = blockIdx.x;
    const int bh = bid & 31;          // b*NH + h
    const int qi = bid >> 5;          // 0..nqt-1
    const int nqt = T / QT;           // 16
    const int qt = (qi < (nqt >> 1)) ? qi : (nqt - 1 - (qi - (nqt >> 1)));
    const int h = bh & 15;
    const int b = bh >> 4;
    const int kv = h / GQ;

    const u16* kg = k16 + ((size_t)b * T * NKV + kv) * HD;
    const u16* vg = vt16 + (size_t)(b * NKV + kv) * HD * T;

    const int krow_in_seg = lane >> 4;          // 0..3
    const int kclog_base = lane & 15;           // phys chunk; logical = phys ^ (r&15)
    const int vrow_in_seg = lane >> 3;          // 0..7
    const int vclog = (lane & 7) ^ (lane >> 3); // logical chunk

    const int q0 = qt * QT;
    const int qglob = q0 + wave * 16 + l16;
    const int nts = q0 / SK + 2;      // two diagonal tiles

    bf16x8 qf[4];
    {
        const u16* qp = q16 + ((size_t)(b * T + qglob) * NH + h) * HD;
#pragma unroll
        for (int kc = 0; kc < 4; kc++)
            qf[kc] = *(const bf16x8*)(qp + kc * 32 + quad * 8);
    }

    f32x4 of[8];
#pragma unroll
    for (int i = 0; i < 8; i++) of[i] = (f32x4){0.f, 0.f, 0.f, 0.f};
    float m_i = -1e30f, l_i = 0.0f;

    // preload tile 0: 16 K segs + 16 V segs, 2+2 per wave
#pragma unroll
    for (int j = 0; j < 2; j++) {
        const int seg = wave * 2 + j;
        const int r = seg * 4 + krow_in_seg;
        const int clog = kclog_base ^ (r & 15);
        ASYNC_LOAD16(kg + (size_t)r * (NKV * HD) + clog * 8, &Ks[0][seg * 512]);
        const int d = seg * 8 + vrow_in_seg;
        ASYNC_LOAD16(vg + (size_t)d * T + vclog * 8, &Vt[0][seg * 512]);
    }

    for (int it = 0; it < nts; it++) {
        const int cur = it & 1;
        __syncthreads();   // drains DMA for tile `it` (one full phase in flight)

        if (it + 1 < nts) {
            const int s1 = (it + 1) * SK;
#pragma unroll
            for (int j = 0; j < 2; j++) {
                const int seg = wave * 2 + j;
                const int r = seg * 4 + krow_in_seg;
                const int clog = kclog_base ^ (r & 15);
                ASYNC_LOAD16(kg + (size_t)(s1 + r) * (NKV * HD) + clog * 8,
                             &Ks[cur ^ 1][seg * 512]);
                const int d = seg * 8 + vrow_in_seg;
                ASYNC_LOAD16(vg + (size_t)d * T + s1 + vclog * 8,
                             &Vt[cur ^ 1][seg * 512]);
            }
        }

        // waves 0-3 are fully masked on the last diagonal tile: skip compute
        if (it == nts - 1 && wave < 4) continue;

        // S^T = K Q^T
        f32x4 sf[4];
#pragma unroll
        for (int st = 0; st < 4; st++) sf[st] = (f32x4){0.f, 0.f, 0.f, 0.f};
#pragma unroll
        for (int kc = 0; kc < 4; kc++)
#pragma unroll
            for (int st = 0; st < 4; st++) {
                const int row = st * 16 + l16;
                bf16x8 kf = *(const bf16x8*)
                    &Ks[cur][row * 128 + (((kc * 4 + quad) ^ l16) * 8)];
                sf[st] = __builtin_amdgcn_mfma_f32_16x16x32_bf16(kf, qf[kc], sf[st], 0, 0, 0);
            }

        if (it >= nts - 2) {  // diagonal tiles: causal mask
            const int s0 = it * SK;
#pragma unroll
            for (int st = 0; st < 4; st++)
#pragma unroll
                for (int r = 0; r < 4; r++)
                    if (s0 + st * 16 + quad * 4 + r > qglob) sf[st][r] = -1e30f;
        }

        float tm = -1e30f;
#pragma unroll
        for (int st = 0; st < 4; st++)
#pragma unroll
            for (int r = 0; r < 4; r++) tm = fmaxf(tm, sf[st][r]);
        tm = fmaxf(tm, __shfl_xor(tm, 16));
        tm = fmaxf(tm, __shfl_xor(tm, 32));

        // defer-max (T13): only rescale when max grew by > 8 (log2 units)
        if (__ballot(tm > m_i + 8.0f)) {
            const float mnew = fmaxf(m_i, tm);
            const float alpha = fast_exp2(m_i - mnew);
            m_i = mnew;
            l_i *= alpha;
#pragma unroll
            for (int dt = 0; dt < 8; dt++)
#pragma unroll
                for (int r = 0; r < 4; r++) of[dt][r] *= alpha;
        }

        f16x4 pf[4];
        float ls = 0.0f;
#pragma unroll
        for (int st = 0; st < 4; st++)
#pragma unroll
            for (int r = 0; r < 4; r++) {
                float e = fast_exp2(sf[st][r] - m_i);
                ls += e;
                pf[st][r] = (_Float16)e;
            }
        ls += __shfl_xor(ls, 16);
        ls += __shfl_xor(ls, 32);
        l_i += ls;

        // O^T += V^T P^T
#pragma unroll
        for (int st = 0; st < 4; st++) {
            const int clog = st * 2 + (quad >> 1);
#pragma unroll
            for (int dt = 0; dt < 8; dt++) {
                const int d = dt * 16 + l16;
                const int phys = clog ^ (l16 & 7);
                f16x4 va = *(const f16x4*)
                    &Vt[cur][d * 64 + phys * 8 + (quad & 1) * 4];
                of[dt] = __builtin_amdgcn_mfma_f32_16x16x16f16(va, pf[st], of[dt], 0, 0, 0);
            }
        }
    }

    const float inv = 1.0f / l_i;
    u16* yp = y16 + ((size_t)(b * T + qglob) * NH + h) * HD + quad * 4;
#pragma unroll
    for (int dt = 0; dt < 8; dt++) {
        ushort4 o;
        o.x = (u16)f2bf(of[dt][0] * inv);
        o.y = (u16)f2bf(of[dt][1] * inv);
        o.z = (u16)f2bf(of[dt][2] * inv);
        o.w = (u16)f2bf(of[dt][3] * inv);
        *(ushort4*)(yp + dt * 16) = o;
    }
}

// ---------------------------------------------------------------------------
extern "C" void kernel_launch(void* const* d_in, const int* in_sizes, int n_in,
                              void* d_out, int out_size, void* d_ws, size_t ws_size,
                              hipStream_t stream) {
    const float* x      = (const float*)d_in[0];
    const float* Wq     = (const float*)d_in[1];
    const float* Wk     = (const float*)d_in[2];
    const float* Wv     = (const float*)d_in[3];
    const float* Wp     = (const float*)d_in[4];
    const float* q_gain = (const float*)d_in[5];
    float* out = (float*)d_out;

    const int B = 2;
    const int BT = in_sizes[0] / DIM;      // 4096
    const int T = BT / B;                  // 2048
    const int KD = NKV * HD;               // 512

    u16* x16   = (u16*)d_ws;                        // BT*DIM        (later y16)
    u16* wqkv  = x16 + (size_t)BT * DIM;            // 3072*DIM
    u16* wp16  = wqkv + (size_t)3072 * DIM;         // DIM*DIM
    u16* q16   = wp16 + (size_t)DIM * DIM;          // BT*DIM
    u16* k16   = q16 + (size_t)BT * DIM;            // BT*KD
    u16* vt16  = k16 + (size_t)BT * KD;             // BT*KD
    float* ctab = (float*)(vt16 + (size_t)BT * KD); // T*64
    float* stab = ctab + (size_t)T * 64;            // T*64
    u16* y16   = x16;

    double base = 10000.0;
    if (T > 1024) base = 10000.0 * pow((double)T / 1024.0, 128.0 / 126.0);
    const float l2b64 = (float)(log2(base) / 64.0);

    const int nx4  = BT * DIM / 4;
    const int total4 = nx4 + 2 * (DIM * DIM / 4) + 2 * (KD * DIM / 4);
    const int nblk_cvt = (total4 + 255) / 256;
    const int nblk_rope = (T * 64 + 255) / 256;

    cvt_fused<<<nblk_cvt + nblk_rope, 256, 0, stream>>>(
        x, Wq, Wk, Wv, Wp, x16, wqkv, wp16, ctab, stab, l2b64, nx4, total4, nblk_cvt);

    gemm32<1, 4><<<dim3(BT / 256, 3072 / BN), 512, 0, stream>>>(
        x16, wqkv, nullptr, 0, q16, k16, vt16, ctab, stab, q_gain, T);

    flash5<<<32 * (T / QT), 512, 0, stream>>>(q16, k16, vt16, y16, T);

    gemm32<0, 2><<<dim3(BT / 128, DIM / BN), 512, 0, stream>>>(
        y16, wp16, out, DIM, nullptr, nullptr, nullptr, nullptr, nullptr, nullptr, T);
}